// Round 8
// baseline (757.502 us; speedup 1.0000x reference)
//
#include <hip/hip_runtime.h>

typedef __attribute__((ext_vector_type(8))) short bf16x8;
typedef __attribute__((ext_vector_type(4))) float f32x4;

__device__ __forceinline__ float bf2f(unsigned short h) {
  return __uint_as_float(((unsigned)h) << 16);
}
// packed fp32->bf16 (RTNE), 1 instr per 2 values
__device__ __forceinline__ unsigned cvtpk(float a, float b) {
  unsigned r;
  asm("v_cvt_pk_bf16_f32 %0, %1, %2" : "=v"(r) : "v"(a), "v"(b));
  return r;
}
__device__ __forceinline__ unsigned short f2bf(float f) {
  return (unsigned short)(cvtpk(f, f) & 0xffffu);
}
__device__ __forceinline__ bf16x8 pack8(f32x4 x0, f32x4 x1) {
  union { bf16x8 v; unsigned u[4]; } z;
  z.u[0] = cvtpk(x0[0], x0[1]);
  z.u[1] = cvtpk(x0[2], x0[3]);
  z.u[2] = cvtpk(x1[0], x1[1]);
  z.u[3] = cvtpk(x1[2], x1[3]);
  return z.v;
}

// ---------------- GEMM64: out[M,64] = A[M,64] @ W[64,64] + b ----------------
template<bool IN_BF16, bool OUT_BF16>
__global__ void __launch_bounds__(256) gemm64_kernel(const void* __restrict__ Ain,
    const float* __restrict__ W, const float* __restrict__ bias,
    void* __restrict__ Out, int M) {
  const int tid = threadIdx.x;
  const int l = tid & 63;
  const int g = l >> 4;
  const int n15 = l & 15;

  bf16x8 bfrag[4][2];
  float bv[4];
#pragma unroll
  for (int nb = 0; nb < 4; ++nb) {
    bv[nb] = bias[nb * 16 + n15];
#pragma unroll
    for (int kb = 0; kb < 2; ++kb)
#pragma unroll
      for (int j = 0; j < 8; ++j)
        bfrag[nb][kb][j] = (short)f2bf(W[(kb * 32 + g * 8 + j) * 64 + nb * 16 + n15]);
  }

  int wid = (blockIdx.x * blockDim.x + tid) >> 6;
  int nw = (gridDim.x * blockDim.x) >> 6;
  int ntiles = (M + 15) >> 4;
  for (int t = wid; t < ntiles; t += nw) {
    int m0 = t << 4;
    int arow = m0 + n15;
    bf16x8 a0, a1;
    if (arow < M) {
      if constexpr (IN_BF16) {
        const unsigned short* ap = (const unsigned short*)Ain + (size_t)arow * 64 + g * 8;
        a0 = *(const bf16x8*)ap;
        a1 = *(const bf16x8*)(ap + 32);
      } else {
        const float* ap = (const float*)Ain + (size_t)arow * 64 + g * 8;
        a0 = pack8(*(const f32x4*)ap, *(const f32x4*)(ap + 4));
        a1 = pack8(*(const f32x4*)(ap + 32), *(const f32x4*)(ap + 36));
      }
    } else {
#pragma unroll
      for (int j = 0; j < 8; ++j) { a0[j] = 0; a1[j] = 0; }
    }
    f32x4 acc[4];
#pragma unroll
    for (int nb = 0; nb < 4; ++nb) {
      acc[nb] = (f32x4){bv[nb], bv[nb], bv[nb], bv[nb]};
      acc[nb] = __builtin_amdgcn_mfma_f32_16x16x32_bf16(a0, bfrag[nb][0], acc[nb], 0, 0, 0);
      acc[nb] = __builtin_amdgcn_mfma_f32_16x16x32_bf16(a1, bfrag[nb][1], acc[nb], 0, 0, 0);
    }
#pragma unroll
    for (int nb = 0; nb < 4; ++nb)
#pragma unroll
      for (int r = 0; r < 4; ++r) {
        int orow = m0 + g * 4 + r;
        if (orow < M) {
          float val = acc[nb][r];
          size_t oidx = (size_t)orow * 64 + nb * 16 + n15;
          if constexpr (OUT_BF16) ((unsigned short*)Out)[oidx] = f2bf(val);
          else                    ((float*)Out)[oidx] = val;
        }
      }
  }
}

// Fused q/k/v: 3 weight sets resident, hx read once, bf16 outputs.
__global__ void __launch_bounds__(256) qkv3_kernel(const float* __restrict__ hx,
    const float* __restrict__ Wq, const float* __restrict__ bq,
    const float* __restrict__ Wk, const float* __restrict__ bk,
    const float* __restrict__ Wv, const float* __restrict__ bv,
    unsigned short* __restrict__ q, unsigned short* __restrict__ k,
    unsigned short* __restrict__ v, int M) {
  const int tid = threadIdx.x;
  const int l = tid & 63;
  const int g = l >> 4;
  const int n15 = l & 15;
  const float* Ws[3] = {Wq, Wk, Wv};
  const float* bs[3] = {bq, bk, bv};
  unsigned short* outs[3] = {q, k, v};

  bf16x8 bfrag[3][4][2];
  float bvv[3][4];
#pragma unroll
  for (int w = 0; w < 3; ++w)
#pragma unroll
    for (int nb = 0; nb < 4; ++nb) {
      bvv[w][nb] = bs[w][nb * 16 + n15];
#pragma unroll
      for (int kb = 0; kb < 2; ++kb)
#pragma unroll
        for (int j = 0; j < 8; ++j)
          bfrag[w][nb][kb][j] = (short)f2bf(Ws[w][(kb * 32 + g * 8 + j) * 64 + nb * 16 + n15]);
    }

  int wid = (blockIdx.x * blockDim.x + tid) >> 6;
  int nw = (gridDim.x * blockDim.x) >> 6;
  int ntiles = (M + 15) >> 4;
  for (int t = wid; t < ntiles; t += nw) {
    int m0 = t << 4;
    int arow = m0 + n15;
    bf16x8 a0, a1;
    if (arow < M) {
      const float* ap = hx + (size_t)arow * 64 + g * 8;
      a0 = pack8(*(const f32x4*)ap, *(const f32x4*)(ap + 4));
      a1 = pack8(*(const f32x4*)(ap + 32), *(const f32x4*)(ap + 36));
    } else {
#pragma unroll
      for (int j = 0; j < 8; ++j) { a0[j] = 0; a1[j] = 0; }
    }
#pragma unroll
    for (int w = 0; w < 3; ++w) {
      f32x4 acc[4];
#pragma unroll
      for (int nb = 0; nb < 4; ++nb) {
        acc[nb] = (f32x4){bvv[w][nb], bvv[w][nb], bvv[w][nb], bvv[w][nb]};
        acc[nb] = __builtin_amdgcn_mfma_f32_16x16x32_bf16(a0, bfrag[w][nb][0], acc[nb], 0, 0, 0);
        acc[nb] = __builtin_amdgcn_mfma_f32_16x16x32_bf16(a1, bfrag[w][nb][1], acc[nb], 0, 0, 0);
      }
#pragma unroll
      for (int nb = 0; nb < 4; ++nb)
#pragma unroll
        for (int r = 0; r < 4; ++r) {
          int orow = m0 + g * 4 + r;
          if (orow < M)
            outs[w][(size_t)orow * 64 + nb * 16 + n15] = f2bf(acc[nb][r]);
        }
    }
  }
}

// ---------------- Fused edge pipeline (pipelined; no block barriers) ----------------
// Wave-local LDS producer->consumer is safe without fences: DS ops of a wave
// complete in order, and the compiler keeps program order for same-array
// ds_write/ds_read (MayAlias) and inserts lgkmcnt before each read's use.
__global__ void __launch_bounds__(256, 4) edge_fused_kernel(
    const float* __restrict__ he,
    const int* __restrict__ rowi, const int* __restrict__ coli,
    const int* __restrict__ eslot,
    const unsigned short* __restrict__ qb, const unsigned short* __restrict__ kbuf,
    const float* __restrict__ We, const float* __restrict__ be,
    const float* __restrict__ Woe, const float* __restrict__ boe,
    float* __restrict__ oe, float* __restrict__ escores, int E) {
  const int tid = threadIdx.x;
  const int wv = tid >> 6;
  const int l = tid & 63;
  const int g = l >> 4;
  const int n15 = l & 15;
  const int h = n15 & 7;

  __shared__ float s_lds[4][160];                 // [wave][row*10 + h]
  __shared__ unsigned short feat_lds[4][16 * 72]; // [wave][row*72 + col]

  bf16x8 bfE[4][2], bfO[4][2];
  float beV[4], boV[4];
#pragma unroll
  for (int nb = 0; nb < 4; ++nb) {
    beV[nb] = be[nb * 16 + n15];
    boV[nb] = boe[nb * 16 + n15];
#pragma unroll
    for (int kb = 0; kb < 2; ++kb)
#pragma unroll
      for (int j = 0; j < 8; ++j) {
        bfE[nb][kb][j] = (short)f2bf(We[(kb * 32 + g * 8 + j) * 64 + nb * 16 + n15]);
        bfO[nb][kb][j] = (short)f2bf(Woe[(kb * 32 + g * 8 + j) * 64 + nb * 16 + n15]);
      }
  }

  const int ntiles = (E + 15) >> 4;
  const int nit = (ntiles + 3) >> 2;
  const int stride = gridDim.x;

  int it = blockIdx.x;
  if (it >= nit) return;

  // prologue: load tile `it`'s he rows + indices
  f32x4 h0, h1, h2, h3;
  int rq, rc, sl;
  {
    int m0 = ((it << 2) + wv) << 4;
    int es = min(m0 + n15, E - 1);
    const float* ap = he + (size_t)es * 64 + g * 8;
    h0 = *(const f32x4*)ap;       h1 = *(const f32x4*)(ap + 4);
    h2 = *(const f32x4*)(ap + 32); h3 = *(const f32x4*)(ap + 36);
    rq = rowi[es]; rc = coli[es]; sl = eslot[es];
  }

  while (true) {
    const int m0 = ((it << 2) + wv) << 4;
    const int arow = m0 + n15;

    // issue q/k gathers for CURRENT tile (addresses arrived last iteration)
    const unsigned short* qp = qb + (size_t)rq * 64 + g * 16;
    const unsigned short* kp = kbuf + (size_t)rc * 64 + g * 16;
    bf16x8 qv0 = *(const bf16x8*)qp, qv1 = *(const bf16x8*)(qp + 8);
    bf16x8 kv0 = *(const bf16x8*)kp, kv1 = *(const bf16x8*)(kp + 8);

    // issue NEXT tile's he + index loads (prefetch)
    const int itn = it + stride;
    const bool more = itn < nit;
    f32x4 nh0 = h0, nh1 = h1, nh2 = h2, nh3 = h3;
    int nrq = rq, nrc = rc, nsl = sl;
    if (more) {
      int m0n = ((itn << 2) + wv) << 4;
      int es = min(m0n + n15, E - 1);
      const float* ap = he + (size_t)es * 64 + g * 8;
      nh0 = *(const f32x4*)ap;       nh1 = *(const f32x4*)(ap + 4);
      nh2 = *(const f32x4*)(ap + 32); nh3 = *(const f32x4*)(ap + 36);
      nrq = rowi[es]; nrc = coli[es]; nsl = eslot[es];
    }

    // ---- compute current tile ----
    bf16x8 a0 = pack8(h0, h1), a1 = pack8(h2, h3);
    if (arow >= E) {
#pragma unroll
      for (int j = 0; j < 8; ++j) { a0[j] = 0; a1[j] = 0; }
    }
    f32x4 acc[4];
#pragma unroll
    for (int nb = 0; nb < 4; ++nb) {
      acc[nb] = (f32x4){beV[nb], beV[nb], beV[nb], beV[nb]};
      acc[nb] = __builtin_amdgcn_mfma_f32_16x16x32_bf16(a0, bfE[nb][0], acc[nb], 0, 0, 0);
      acc[nb] = __builtin_amdgcn_mfma_f32_16x16x32_bf16(a1, bfE[nb][1], acc[nb], 0, 0, 0);
    }
    // per-head gate: sum nb-quadrants, pair n15 <-> n15+8; fold 1/sqrt(8)
    float gc[4];
#pragma unroll
    for (int r = 0; r < 4; ++r) {
      float s = acc[0][r] + acc[1][r] + acc[2][r] + acc[3][r];
      s += __shfl_xor(s, 8, 64);
      gc[r] = s * 0.35355339059327373f;
    }
    // tiled q.k: lane covers cols g*16..g*16+15 of edge m0+n15
    float p[8];
#pragma unroll
    for (int j = 0; j < 8; ++j)
      p[j] = bf2f((unsigned short)qv0[j]) * bf2f((unsigned short)kv0[j])
           + bf2f((unsigned short)qv1[j]) * bf2f((unsigned short)kv1[j]);
#pragma unroll
    for (int j = 0; j < 8; ++j) {
      p[j] += __shfl_xor(p[j], 16, 64);
      p[j] += __shfl_xor(p[j], 32, 64);
    }
    // p -> LDS (edge-row layout), re-read in C-row layout (wave-local, in-order DS)
    if (l < 16) {
      float2* sp = (float2*)&s_lds[wv][n15 * 10];
#pragma unroll
      for (int j = 0; j < 4; ++j) sp[j] = make_float2(p[2 * j], p[2 * j + 1]);
    }
    float srow[4];
#pragma unroll
    for (int r = 0; r < 4; ++r)
      srow[r] = s_lds[wv][(g * 4 + r) * 10 + h] * gc[r];
    // gated scores out, directly into CSR slot order
#pragma unroll
    for (int r = 0; r < 4; ++r) {
      int orow = m0 + g * 4 + r;
      int slot = __shfl(sl, g * 4 + r, 64);
      if (n15 < 8 && orow < E) escores[(size_t)slot * 8 + n15] = srow[r];
    }
    // feat = s*elin -> LDS transpose tile
#pragma unroll
    for (int nb = 0; nb < 4; ++nb)
#pragma unroll
      for (int r = 0; r < 4; ++r)
        feat_lds[wv][(g * 4 + r) * 72 + nb * 16 + n15] = f2bf(srow[r] * acc[nb][r]);
    const unsigned short* fpt = &feat_lds[wv][n15 * 72 + g * 8];
    a0 = *(const bf16x8*)fpt;
    a1 = *(const bf16x8*)(fpt + 32);
#pragma unroll
    for (int nb = 0; nb < 4; ++nb) {
      f32x4 a2 = (f32x4){boV[nb], boV[nb], boV[nb], boV[nb]};
      a2 = __builtin_amdgcn_mfma_f32_16x16x32_bf16(a0, bfO[nb][0], a2, 0, 0, 0);
      a2 = __builtin_amdgcn_mfma_f32_16x16x32_bf16(a1, bfO[nb][1], a2, 0, 0, 0);
#pragma unroll
      for (int r = 0; r < 4; ++r) {
        int orow = m0 + g * 4 + r;
        if (orow < E) oe[(size_t)orow * 64 + nb * 16 + n15] = a2[r];
      }
    }

    if (!more) break;
    h0 = nh0; h1 = nh1; h2 = nh2; h3 = nh3;
    rq = nrq; rc = nrc; sl = nsl;
    it = itn;
  }
}

// ---------------- CSR build ----------------
__global__ void zero_kernel(int* __restrict__ p, int n) {
  int i = blockIdx.x * blockDim.x + threadIdx.x;
  if (i < n) p[i] = 0;
}

__global__ void hist_kernel(const int* __restrict__ row, int* __restrict__ deg, int E) {
  int gid = blockIdx.x * blockDim.x + threadIdx.x;
  if (gid < E) atomicAdd(&deg[row[gid]], 1);
}

#define SCAN_B 256
#define SCAN_E 8
__global__ void scan1_kernel(const int* __restrict__ deg, int* __restrict__ rowptr,
                             int* __restrict__ blksum, int n) {
  __shared__ int sh[SCAN_B];
  int base = blockIdx.x * (SCAN_B * SCAN_E) + threadIdx.x * SCAN_E;
  int v[SCAN_E];
  int s = 0;
#pragma unroll
  for (int j = 0; j < SCAN_E; ++j) {
    v[j] = (base + j < n) ? deg[base + j] : 0;
    s += v[j];
  }
  sh[threadIdx.x] = s;
  __syncthreads();
  for (int off = 1; off < SCAN_B; off <<= 1) {
    int t = (threadIdx.x >= off) ? sh[threadIdx.x - off] : 0;
    __syncthreads();
    sh[threadIdx.x] += t;
    __syncthreads();
  }
  if (threadIdx.x == SCAN_B - 1) blksum[blockIdx.x] = sh[SCAN_B - 1];
  int run = sh[threadIdx.x] - s;
#pragma unroll
  for (int j = 0; j < SCAN_E; ++j) {
    if (base + j < n) rowptr[base + j] = run;
    run += v[j];
  }
}

__global__ void scan2_kernel(int* __restrict__ blksum, int nb) {
  __shared__ int sh[SCAN_B];
  int v = (threadIdx.x < nb) ? blksum[threadIdx.x] : 0;
  sh[threadIdx.x] = v;
  __syncthreads();
  for (int off = 1; off < SCAN_B; off <<= 1) {
    int t = (threadIdx.x >= off) ? sh[threadIdx.x - off] : 0;
    __syncthreads();
    sh[threadIdx.x] += t;
    __syncthreads();
  }
  if (threadIdx.x < nb) blksum[threadIdx.x] = sh[threadIdx.x] - v;
}

__global__ void scan3_kernel(int* __restrict__ rowptr, int* __restrict__ cursor,
                             const int* __restrict__ blksum, int n) {
  int i = blockIdx.x * blockDim.x + threadIdx.x;
  if (i >= n) return;
  int v = rowptr[i] + blksum[i / (SCAN_B * SCAN_E)];
  rowptr[i] = v;
  cursor[i] = v;
}

// records eslot[e] so scores can be written in CSR order by edge_fused
__global__ void scatter_kernel(const int* __restrict__ row, const int* __restrict__ col,
                               int* __restrict__ cursor, int* __restrict__ eslot,
                               int* __restrict__ ecol, int E) {
  int gid = blockIdx.x * blockDim.x + threadIdx.x;
  if (gid >= E) return;
  int r = row[gid];
  int slot = atomicAdd(&cursor[r], 1);
  eslot[gid] = slot;
  ecol[slot] = col[gid];
}

// One wave per row. Scores are pre-gated and small: softmax without max-shift
// is numerically safe in fp32; independent iterations -> full ILP.
__global__ void __launch_bounds__(256) row_attn_kernel(const float* __restrict__ escores,
    const int* __restrict__ rowptr, const int* __restrict__ deg,
    const int* __restrict__ ecol,
    const unsigned short* __restrict__ vb, float* __restrict__ hout, int n) {
  int gid = blockIdx.x * blockDim.x + threadIdx.x;
  int r = gid >> 6, lane = threadIdx.x & 63;
  if (r >= n) return;
  int start = rowptr[r], dg = deg[r];
  int h = lane & 7;
  float den = 0.f, acc = 0.f;
#pragma unroll 4
  for (int i = 0; i < dg; ++i) {
    int c = ecol[start + i];
    float ex = __expf(escores[(size_t)(start + i) * 8 + h]);
    float vv = bf2f(vb[(size_t)c * 64 + lane]);
    den += ex;
    acc += ex * vv;
  }
  hout[(size_t)r * 64 + lane] = (dg > 0) ? acc / den : 0.f;
}

extern "C" void kernel_launch(void* const* d_in, const int* in_sizes, int n_in,
                              void* d_out, int out_size, void* d_ws, size_t ws_size,
                              hipStream_t stream) {
  const float* hx  = (const float*)d_in[0];
  const float* he  = (const float*)d_in[1];
  const int*   row = (const int*)d_in[2];
  const int*   col = (const int*)d_in[3];
  const float* Wq = (const float*)d_in[4],  *bq = (const float*)d_in[5];
  const float* Wk = (const float*)d_in[6],  *bk = (const float*)d_in[7];
  const float* Wv = (const float*)d_in[8],  *bv = (const float*)d_in[9];
  const float* We = (const float*)d_in[10], *be = (const float*)d_in[11];
  const float* Woh = (const float*)d_in[12], *boh = (const float*)d_in[13];
  const float* Woe = (const float*)d_in[14], *boe = (const float*)d_in[15];

  const int n = in_sizes[0] / 64;
  const int E = in_sizes[2];

  float* out = (float*)d_out;
  float* oh = out;                   // n*64 fp32
  float* oe = out + (size_t)n * 64;  // E*64 fp32

  // ws: qb,kb,vbuf (n*64 bf16) | escores (E*8 f32, CSR order) | hout (n*64 f32)
  //   | deg,rowptr,cursor (n int) | blksum (256) | eslot (E) | ecol (E)
  unsigned short* qb   = (unsigned short*)d_ws;
  unsigned short* kb   = qb + (size_t)n * 64;
  unsigned short* vbuf = kb + (size_t)n * 64;
  float* escores = (float*)(vbuf + (size_t)n * 64);
  float* hout    = escores + (size_t)E * 8;

  int* deg    = (int*)(hout + (size_t)n * 64);
  int* rowptr = deg + n;
  int* cursor = rowptr + n;
  int* blksum = cursor + n;
  int* eslot  = blksum + 256;
  int* ecol   = eslot + (size_t)E;

  const int nb_scan = (n + SCAN_B * SCAN_E - 1) / (SCAN_B * SCAN_E);

  // CSR build first (depends only on row/col) so edge_fused can scatter scores.
  zero_kernel<<<(n + 255) / 256, 256, 0, stream>>>(deg, n);
  hist_kernel<<<(E + 255) / 256, 256, 0, stream>>>(row, deg, E);
  scan1_kernel<<<nb_scan, SCAN_B, 0, stream>>>(deg, rowptr, blksum, n);
  scan2_kernel<<<1, SCAN_B, 0, stream>>>(blksum, nb_scan);
  scan3_kernel<<<(n + 255) / 256, 256, 0, stream>>>(rowptr, cursor, blksum, n);
  scatter_kernel<<<(E + 255) / 256, 256, 0, stream>>>(row, col, cursor, eslot, ecol, E);

  qkv3_kernel<<<512, 256, 0, stream>>>(hx, Wq, bq, Wk, bk, Wv, bv, qb, kb, vbuf, n);
  edge_fused_kernel<<<2048, 256, 0, stream>>>(he, row, col, eslot, qb, kb, We, be,
                                              Woe, boe, oe, escores, E);

  row_attn_kernel<<<(n + 3) / 4, 256, 0, stream>>>(escores, rowptr, deg, ecol,
                                                   vbuf, hout, n);
  gemm64_kernel<false, false><<<512, 256, 0, stream>>>(hout, Woh, boh, oh, n);
}

// Round 9
// 550.800 us; speedup vs baseline: 1.3753x; 1.3753x over previous
//
#include <hip/hip_runtime.h>

typedef __attribute__((ext_vector_type(8))) short bf16x8;
typedef __attribute__((ext_vector_type(4))) float f32x4;

__device__ __forceinline__ float bf2f(unsigned short h) {
  return __uint_as_float(((unsigned)h) << 16);
}
// packed fp32->bf16 (RTNE), 1 instr per 2 values
__device__ __forceinline__ unsigned cvtpk(float a, float b) {
  unsigned r;
  asm("v_cvt_pk_bf16_f32 %0, %1, %2" : "=v"(r) : "v"(a), "v"(b));
  return r;
}
__device__ __forceinline__ unsigned short f2bf(float f) {
  return (unsigned short)(cvtpk(f, f) & 0xffffu);
}
__device__ __forceinline__ bf16x8 pack8(f32x4 x0, f32x4 x1) {
  union { bf16x8 v; unsigned u[4]; } z;
  z.u[0] = cvtpk(x0[0], x0[1]);
  z.u[1] = cvtpk(x0[2], x0[3]);
  z.u[2] = cvtpk(x1[0], x1[1]);
  z.u[3] = cvtpk(x1[2], x1[3]);
  return z.v;
}

// ---------------- GEMM64: out[M,64] = A[M,64] @ W[64,64] + b ----------------
template<bool IN_BF16, bool OUT_BF16>
__global__ void __launch_bounds__(256) gemm64_kernel(const void* __restrict__ Ain,
    const float* __restrict__ W, const float* __restrict__ bias,
    void* __restrict__ Out, int M) {
  const int tid = threadIdx.x;
  const int l = tid & 63;
  const int g = l >> 4;
  const int n15 = l & 15;

  bf16x8 bfrag[4][2];
  float bv[4];
#pragma unroll
  for (int nb = 0; nb < 4; ++nb) {
    bv[nb] = bias[nb * 16 + n15];
#pragma unroll
    for (int kb = 0; kb < 2; ++kb)
#pragma unroll
      for (int j = 0; j < 8; ++j)
        bfrag[nb][kb][j] = (short)f2bf(W[(kb * 32 + g * 8 + j) * 64 + nb * 16 + n15]);
  }

  int wid = (blockIdx.x * blockDim.x + tid) >> 6;
  int nw = (gridDim.x * blockDim.x) >> 6;
  int ntiles = (M + 15) >> 4;
  for (int t = wid; t < ntiles; t += nw) {
    int m0 = t << 4;
    int arow = m0 + n15;
    bf16x8 a0, a1;
    if (arow < M) {
      if constexpr (IN_BF16) {
        const unsigned short* ap = (const unsigned short*)Ain + (size_t)arow * 64 + g * 8;
        a0 = *(const bf16x8*)ap;
        a1 = *(const bf16x8*)(ap + 32);
      } else {
        const float* ap = (const float*)Ain + (size_t)arow * 64 + g * 8;
        a0 = pack8(*(const f32x4*)ap, *(const f32x4*)(ap + 4));
        a1 = pack8(*(const f32x4*)(ap + 32), *(const f32x4*)(ap + 36));
      }
    } else {
#pragma unroll
      for (int j = 0; j < 8; ++j) { a0[j] = 0; a1[j] = 0; }
    }
    f32x4 acc[4];
#pragma unroll
    for (int nb = 0; nb < 4; ++nb) {
      acc[nb] = (f32x4){bv[nb], bv[nb], bv[nb], bv[nb]};
      acc[nb] = __builtin_amdgcn_mfma_f32_16x16x32_bf16(a0, bfrag[nb][0], acc[nb], 0, 0, 0);
      acc[nb] = __builtin_amdgcn_mfma_f32_16x16x32_bf16(a1, bfrag[nb][1], acc[nb], 0, 0, 0);
    }
#pragma unroll
    for (int nb = 0; nb < 4; ++nb)
#pragma unroll
      for (int r = 0; r < 4; ++r) {
        int orow = m0 + g * 4 + r;
        if (orow < M) {
          float val = acc[nb][r];
          size_t oidx = (size_t)orow * 64 + nb * 16 + n15;
          if constexpr (OUT_BF16) ((unsigned short*)Out)[oidx] = f2bf(val);
          else                    ((float*)Out)[oidx] = val;
        }
      }
  }
}

// Fused q/k/v: 3 weight sets resident, hx read once, bf16 outputs.
__global__ void __launch_bounds__(256) qkv3_kernel(const float* __restrict__ hx,
    const float* __restrict__ Wq, const float* __restrict__ bq,
    const float* __restrict__ Wk, const float* __restrict__ bk,
    const float* __restrict__ Wv, const float* __restrict__ bv,
    unsigned short* __restrict__ q, unsigned short* __restrict__ k,
    unsigned short* __restrict__ v, int M) {
  const int tid = threadIdx.x;
  const int l = tid & 63;
  const int g = l >> 4;
  const int n15 = l & 15;
  const float* Ws[3] = {Wq, Wk, Wv};
  const float* bs[3] = {bq, bk, bv};
  unsigned short* outs[3] = {q, k, v};

  bf16x8 bfrag[3][4][2];
  float bvv[3][4];
#pragma unroll
  for (int w = 0; w < 3; ++w)
#pragma unroll
    for (int nb = 0; nb < 4; ++nb) {
      bvv[w][nb] = bs[w][nb * 16 + n15];
#pragma unroll
      for (int kb = 0; kb < 2; ++kb)
#pragma unroll
        for (int j = 0; j < 8; ++j)
          bfrag[w][nb][kb][j] = (short)f2bf(Ws[w][(kb * 32 + g * 8 + j) * 64 + nb * 16 + n15]);
    }

  int wid = (blockIdx.x * blockDim.x + tid) >> 6;
  int nw = (gridDim.x * blockDim.x) >> 6;
  int ntiles = (M + 15) >> 4;
  for (int t = wid; t < ntiles; t += nw) {
    int m0 = t << 4;
    int arow = m0 + n15;
    bf16x8 a0, a1;
    if (arow < M) {
      const float* ap = hx + (size_t)arow * 64 + g * 8;
      a0 = pack8(*(const f32x4*)ap, *(const f32x4*)(ap + 4));
      a1 = pack8(*(const f32x4*)(ap + 32), *(const f32x4*)(ap + 36));
    } else {
#pragma unroll
      for (int j = 0; j < 8; ++j) { a0[j] = 0; a1[j] = 0; }
    }
#pragma unroll
    for (int w = 0; w < 3; ++w) {
      f32x4 acc[4];
#pragma unroll
      for (int nb = 0; nb < 4; ++nb) {
        acc[nb] = (f32x4){bvv[w][nb], bvv[w][nb], bvv[w][nb], bvv[w][nb]};
        acc[nb] = __builtin_amdgcn_mfma_f32_16x16x32_bf16(a0, bfrag[w][nb][0], acc[nb], 0, 0, 0);
        acc[nb] = __builtin_amdgcn_mfma_f32_16x16x32_bf16(a1, bfrag[w][nb][1], acc[nb], 0, 0, 0);
      }
#pragma unroll
      for (int nb = 0; nb < 4; ++nb)
#pragma unroll
        for (int r = 0; r < 4; ++r) {
          int orow = m0 + g * 4 + r;
          if (orow < M)
            outs[w][(size_t)orow * 64 + nb * 16 + n15] = f2bf(acc[nb][r]);
        }
    }
  }
}

// ---------------- Fused edge pipeline (pipelined; fence-free wave-local LDS) --------
// NOTE: no launch_bounds min-occupancy — round 8 proved clamping to 64 VGPR spills
// the prefetch registers to scratch (+950 MB HBM). Let the compiler take ~120 VGPR.
__global__ void __launch_bounds__(256) edge_fused_kernel(
    const float* __restrict__ he,
    const int* __restrict__ rowi, const int* __restrict__ coli,
    const int* __restrict__ eslot,
    const unsigned short* __restrict__ qb, const unsigned short* __restrict__ kbuf,
    const float* __restrict__ We, const float* __restrict__ be,
    const float* __restrict__ Woe, const float* __restrict__ boe,
    float* __restrict__ oe, float* __restrict__ escores, int E) {
  const int tid = threadIdx.x;
  const int wv = tid >> 6;
  const int l = tid & 63;
  const int g = l >> 4;
  const int n15 = l & 15;
  const int h = n15 & 7;

  __shared__ float s_lds[4][160];                 // [wave][row*10 + h]
  __shared__ unsigned short feat_lds[4][16 * 72]; // [wave][row*72 + col]

  bf16x8 bfE[4][2], bfO[4][2];
  float beV[4], boV[4];
#pragma unroll
  for (int nb = 0; nb < 4; ++nb) {
    beV[nb] = be[nb * 16 + n15];
    boV[nb] = boe[nb * 16 + n15];
#pragma unroll
    for (int kb = 0; kb < 2; ++kb)
#pragma unroll
      for (int j = 0; j < 8; ++j) {
        bfE[nb][kb][j] = (short)f2bf(We[(kb * 32 + g * 8 + j) * 64 + nb * 16 + n15]);
        bfO[nb][kb][j] = (short)f2bf(Woe[(kb * 32 + g * 8 + j) * 64 + nb * 16 + n15]);
      }
  }

  const int ntiles = (E + 15) >> 4;
  const int nit = (ntiles + 3) >> 2;
  const int stride = gridDim.x;

  int it = blockIdx.x;
  if (it >= nit) return;

  // prologue: load tile `it`'s he rows + indices
  f32x4 h0, h1, h2, h3;
  int rq, rc, sl;
  {
    int m0 = ((it << 2) + wv) << 4;
    int es = min(m0 + n15, E - 1);
    const float* ap = he + (size_t)es * 64 + g * 8;
    h0 = *(const f32x4*)ap;       h1 = *(const f32x4*)(ap + 4);
    h2 = *(const f32x4*)(ap + 32); h3 = *(const f32x4*)(ap + 36);
    rq = rowi[es]; rc = coli[es]; sl = eslot[es];
  }

  while (true) {
    const int m0 = ((it << 2) + wv) << 4;
    const int arow = m0 + n15;

    // issue q/k gathers for CURRENT tile (addresses arrived last iteration)
    const unsigned short* qp = qb + (size_t)rq * 64 + g * 16;
    const unsigned short* kp = kbuf + (size_t)rc * 64 + g * 16;
    bf16x8 qv0 = *(const bf16x8*)qp, qv1 = *(const bf16x8*)(qp + 8);
    bf16x8 kv0 = *(const bf16x8*)kp, kv1 = *(const bf16x8*)(kp + 8);

    // issue NEXT tile's he + index loads (prefetch)
    const int itn = it + stride;
    const bool more = itn < nit;
    f32x4 nh0 = h0, nh1 = h1, nh2 = h2, nh3 = h3;
    int nrq = rq, nrc = rc, nsl = sl;
    if (more) {
      int m0n = ((itn << 2) + wv) << 4;
      int es = min(m0n + n15, E - 1);
      const float* ap = he + (size_t)es * 64 + g * 8;
      nh0 = *(const f32x4*)ap;       nh1 = *(const f32x4*)(ap + 4);
      nh2 = *(const f32x4*)(ap + 32); nh3 = *(const f32x4*)(ap + 36);
      nrq = rowi[es]; nrc = coli[es]; nsl = eslot[es];
    }

    // ---- compute current tile ----
    bf16x8 a0 = pack8(h0, h1), a1 = pack8(h2, h3);
    if (arow >= E) {
#pragma unroll
      for (int j = 0; j < 8; ++j) { a0[j] = 0; a1[j] = 0; }
    }
    f32x4 acc[4];
#pragma unroll
    for (int nb = 0; nb < 4; ++nb) {
      acc[nb] = (f32x4){beV[nb], beV[nb], beV[nb], beV[nb]};
      acc[nb] = __builtin_amdgcn_mfma_f32_16x16x32_bf16(a0, bfE[nb][0], acc[nb], 0, 0, 0);
      acc[nb] = __builtin_amdgcn_mfma_f32_16x16x32_bf16(a1, bfE[nb][1], acc[nb], 0, 0, 0);
    }
    // per-head gate: sum nb-quadrants, pair n15 <-> n15+8; fold 1/sqrt(8)
    float gc[4];
#pragma unroll
    for (int r = 0; r < 4; ++r) {
      float s = acc[0][r] + acc[1][r] + acc[2][r] + acc[3][r];
      s += __shfl_xor(s, 8, 64);
      gc[r] = s * 0.35355339059327373f;
    }
    // tiled q.k: lane covers cols g*16..g*16+15 of edge m0+n15
    float p[8];
#pragma unroll
    for (int j = 0; j < 8; ++j)
      p[j] = bf2f((unsigned short)qv0[j]) * bf2f((unsigned short)kv0[j])
           + bf2f((unsigned short)qv1[j]) * bf2f((unsigned short)kv1[j]);
#pragma unroll
    for (int j = 0; j < 8; ++j) {
      p[j] += __shfl_xor(p[j], 16, 64);
      p[j] += __shfl_xor(p[j], 32, 64);
    }
    // p -> LDS (edge-row layout), re-read in C-row layout (wave-local, in-order DS)
    if (l < 16) {
      float2* sp = (float2*)&s_lds[wv][n15 * 10];
#pragma unroll
      for (int j = 0; j < 4; ++j) sp[j] = make_float2(p[2 * j], p[2 * j + 1]);
    }
    float srow[4];
#pragma unroll
    for (int r = 0; r < 4; ++r)
      srow[r] = s_lds[wv][(g * 4 + r) * 10 + h] * gc[r];
    // gated scores out, directly into CSR slot order
#pragma unroll
    for (int r = 0; r < 4; ++r) {
      int orow = m0 + g * 4 + r;
      int slot = __shfl(sl, g * 4 + r, 64);
      if (n15 < 8 && orow < E) escores[(size_t)slot * 8 + n15] = srow[r];
    }
    // feat = s*elin -> LDS transpose tile
#pragma unroll
    for (int nb = 0; nb < 4; ++nb)
#pragma unroll
      for (int r = 0; r < 4; ++r)
        feat_lds[wv][(g * 4 + r) * 72 + nb * 16 + n15] = f2bf(srow[r] * acc[nb][r]);
    const unsigned short* fpt = &feat_lds[wv][n15 * 72 + g * 8];
    a0 = *(const bf16x8*)fpt;
    a1 = *(const bf16x8*)(fpt + 32);
#pragma unroll
    for (int nb = 0; nb < 4; ++nb) {
      f32x4 a2 = (f32x4){boV[nb], boV[nb], boV[nb], boV[nb]};
      a2 = __builtin_amdgcn_mfma_f32_16x16x32_bf16(a0, bfO[nb][0], a2, 0, 0, 0);
      a2 = __builtin_amdgcn_mfma_f32_16x16x32_bf16(a1, bfO[nb][1], a2, 0, 0, 0);
#pragma unroll
      for (int r = 0; r < 4; ++r) {
        int orow = m0 + g * 4 + r;
        if (orow < E) oe[(size_t)orow * 64 + nb * 16 + n15] = a2[r];
      }
    }

    if (!more) break;
    h0 = nh0; h1 = nh1; h2 = nh2; h3 = nh3;
    rq = nrq; rc = nrc; sl = nsl;
    it = itn;
  }
}

// ---------------- CSR build ----------------
__global__ void zero_kernel(int* __restrict__ p, int n) {
  int i = blockIdx.x * blockDim.x + threadIdx.x;
  if (i < n) p[i] = 0;
}

__global__ void hist_kernel(const int* __restrict__ row, int* __restrict__ deg, int E) {
  int gid = blockIdx.x * blockDim.x + threadIdx.x;
  if (gid < E) atomicAdd(&deg[row[gid]], 1);
}

#define SCAN_B 256
#define SCAN_E 8
__global__ void scan1_kernel(const int* __restrict__ deg, int* __restrict__ rowptr,
                             int* __restrict__ blksum, int n) {
  __shared__ int sh[SCAN_B];
  int base = blockIdx.x * (SCAN_B * SCAN_E) + threadIdx.x * SCAN_E;
  int v[SCAN_E];
  int s = 0;
#pragma unroll
  for (int j = 0; j < SCAN_E; ++j) {
    v[j] = (base + j < n) ? deg[base + j] : 0;
    s += v[j];
  }
  sh[threadIdx.x] = s;
  __syncthreads();
  for (int off = 1; off < SCAN_B; off <<= 1) {
    int t = (threadIdx.x >= off) ? sh[threadIdx.x - off] : 0;
    __syncthreads();
    sh[threadIdx.x] += t;
    __syncthreads();
  }
  if (threadIdx.x == SCAN_B - 1) blksum[blockIdx.x] = sh[SCAN_B - 1];
  int run = sh[threadIdx.x] - s;
#pragma unroll
  for (int j = 0; j < SCAN_E; ++j) {
    if (base + j < n) rowptr[base + j] = run;
    run += v[j];
  }
}

__global__ void scan2_kernel(int* __restrict__ blksum, int nb) {
  __shared__ int sh[SCAN_B];
  int v = (threadIdx.x < nb) ? blksum[threadIdx.x] : 0;
  sh[threadIdx.x] = v;
  __syncthreads();
  for (int off = 1; off < SCAN_B; off <<= 1) {
    int t = (threadIdx.x >= off) ? sh[threadIdx.x - off] : 0;
    __syncthreads();
    sh[threadIdx.x] += t;
    __syncthreads();
  }
  if (threadIdx.x < nb) blksum[threadIdx.x] = sh[threadIdx.x] - v;
}

__global__ void scan3_kernel(int* __restrict__ rowptr, int* __restrict__ cursor,
                             const int* __restrict__ blksum, int n) {
  int i = blockIdx.x * blockDim.x + threadIdx.x;
  if (i >= n) return;
  int v = rowptr[i] + blksum[i / (SCAN_B * SCAN_E)];
  rowptr[i] = v;
  cursor[i] = v;
}

// records eslot[e] so scores can be written in CSR order by edge_fused
__global__ void scatter_kernel(const int* __restrict__ row, const int* __restrict__ col,
                               int* __restrict__ cursor, int* __restrict__ eslot,
                               int* __restrict__ ecol, int E) {
  int gid = blockIdx.x * blockDim.x + threadIdx.x;
  if (gid >= E) return;
  int r = row[gid];
  int slot = atomicAdd(&cursor[r], 1);
  eslot[gid] = slot;
  ecol[slot] = col[gid];
}

// One wave per row. Scores are pre-gated and small: softmax without max-shift
// is numerically safe in fp32; independent iterations -> full ILP.
__global__ void __launch_bounds__(256) row_attn_kernel(const float* __restrict__ escores,
    const int* __restrict__ rowptr, const int* __restrict__ deg,
    const int* __restrict__ ecol,
    const unsigned short* __restrict__ vb, float* __restrict__ hout, int n) {
  int gid = blockIdx.x * blockDim.x + threadIdx.x;
  int r = gid >> 6, lane = threadIdx.x & 63;
  if (r >= n) return;
  int start = rowptr[r], dg = deg[r];
  int h = lane & 7;
  float den = 0.f, acc = 0.f;
#pragma unroll 4
  for (int i = 0; i < dg; ++i) {
    int c = ecol[start + i];
    float ex = __expf(escores[(size_t)(start + i) * 8 + h]);
    float vv = bf2f(vb[(size_t)c * 64 + lane]);
    den += ex;
    acc += ex * vv;
  }
  hout[(size_t)r * 64 + lane] = (dg > 0) ? acc / den : 0.f;
}

extern "C" void kernel_launch(void* const* d_in, const int* in_sizes, int n_in,
                              void* d_out, int out_size, void* d_ws, size_t ws_size,
                              hipStream_t stream) {
  const float* hx  = (const float*)d_in[0];
  const float* he  = (const float*)d_in[1];
  const int*   row = (const int*)d_in[2];
  const int*   col = (const int*)d_in[3];
  const float* Wq = (const float*)d_in[4],  *bq = (const float*)d_in[5];
  const float* Wk = (const float*)d_in[6],  *bk = (const float*)d_in[7];
  const float* Wv = (const float*)d_in[8],  *bv = (const float*)d_in[9];
  const float* We = (const float*)d_in[10], *be = (const float*)d_in[11];
  const float* Woh = (const float*)d_in[12], *boh = (const float*)d_in[13];
  const float* Woe = (const float*)d_in[14], *boe = (const float*)d_in[15];

  const int n = in_sizes[0] / 64;
  const int E = in_sizes[2];

  float* out = (float*)d_out;
  float* oh = out;                   // n*64 fp32
  float* oe = out + (size_t)n * 64;  // E*64 fp32

  // ws: qb,kb,vbuf (n*64 bf16) | escores (E*8 f32, CSR order) | hout (n*64 f32)
  //   | deg,rowptr,cursor (n int) | blksum (256) | eslot (E) | ecol (E)
  unsigned short* qb   = (unsigned short*)d_ws;
  unsigned short* kb   = qb + (size_t)n * 64;
  unsigned short* vbuf = kb + (size_t)n * 64;
  float* escores = (float*)(vbuf + (size_t)n * 64);
  float* hout    = escores + (size_t)E * 8;

  int* deg    = (int*)(hout + (size_t)n * 64);
  int* rowptr = deg + n;
  int* cursor = rowptr + n;
  int* blksum = cursor + n;
  int* eslot  = blksum + 256;
  int* ecol   = eslot + (size_t)E;

  const int nb_scan = (n + SCAN_B * SCAN_E - 1) / (SCAN_B * SCAN_E);

  // CSR build first (depends only on row/col) so edge_fused can scatter scores.
  zero_kernel<<<(n + 255) / 256, 256, 0, stream>>>(deg, n);
  hist_kernel<<<(E + 255) / 256, 256, 0, stream>>>(row, deg, E);
  scan1_kernel<<<nb_scan, SCAN_B, 0, stream>>>(deg, rowptr, blksum, n);
  scan2_kernel<<<1, SCAN_B, 0, stream>>>(blksum, nb_scan);
  scan3_kernel<<<(n + 255) / 256, 256, 0, stream>>>(rowptr, cursor, blksum, n);
  scatter_kernel<<<(E + 255) / 256, 256, 0, stream>>>(row, col, cursor, eslot, ecol, E);

  qkv3_kernel<<<512, 256, 0, stream>>>(hx, Wq, bq, Wk, bk, Wv, bv, qb, kb, vbuf, n);
  edge_fused_kernel<<<2048, 256, 0, stream>>>(he, row, col, eslot, qb, kb, We, be,
                                              Woe, boe, oe, escores, E);

  row_attn_kernel<<<(n + 3) / 4, 256, 0, stream>>>(escores, rowptr, deg, ecol,
                                                   vbuf, hout, n);
  gemm64_kernel<false, false><<<512, 256, 0, stream>>>(hout, Woh, boh, oh, n);
}

// Round 10
// 548.635 us; speedup vs baseline: 1.3807x; 1.0039x over previous
//
#include <hip/hip_runtime.h>

typedef __attribute__((ext_vector_type(8))) short bf16x8;
typedef __attribute__((ext_vector_type(4))) float f32x4;
typedef __attribute__((ext_vector_type(4))) unsigned short u16x4;

__device__ __forceinline__ float bf2f(unsigned short h) {
  return __uint_as_float(((unsigned)h) << 16);
}
// packed fp32->bf16 (RTNE)
__device__ __forceinline__ unsigned cvtpk(float a, float b) {
  unsigned r;
  asm("v_cvt_pk_bf16_f32 %0, %1, %2" : "=v"(r) : "v"(a), "v"(b));
  return r;
}
__device__ __forceinline__ unsigned short f2bf(float f) {
  return (unsigned short)(cvtpk(f, f) & 0xffffu);
}
__device__ __forceinline__ bf16x8 pack8(f32x4 x0, f32x4 x1) {
  union { bf16x8 v; unsigned u[4]; } z;
  z.u[0] = cvtpk(x0[0], x0[1]);
  z.u[1] = cvtpk(x0[2], x0[3]);
  z.u[2] = cvtpk(x1[0], x1[1]);
  z.u[3] = cvtpk(x1[2], x1[3]);
  return z.v;
}

// ---------------- GEMM64: out[M,64] = A[M,64] @ W[64,64] + b ----------------
template<bool IN_BF16, bool OUT_BF16>
__global__ void __launch_bounds__(256) gemm64_kernel(const void* __restrict__ Ain,
    const float* __restrict__ W, const float* __restrict__ bias,
    void* __restrict__ Out, int M) {
  const int tid = threadIdx.x;
  const int l = tid & 63;
  const int g = l >> 4;
  const int n15 = l & 15;

  bf16x8 bfrag[4][2];
  float bv[4];
#pragma unroll
  for (int nb = 0; nb < 4; ++nb) {
    bv[nb] = bias[nb * 16 + n15];
#pragma unroll
    for (int kb = 0; kb < 2; ++kb)
#pragma unroll
      for (int j = 0; j < 8; ++j)
        bfrag[nb][kb][j] = (short)f2bf(W[(kb * 32 + g * 8 + j) * 64 + nb * 16 + n15]);
  }

  int wid = (blockIdx.x * blockDim.x + tid) >> 6;
  int nw = (gridDim.x * blockDim.x) >> 6;
  int ntiles = (M + 15) >> 4;
  for (int t = wid; t < ntiles; t += nw) {
    int m0 = t << 4;
    int arow = m0 + n15;
    bf16x8 a0, a1;
    if (arow < M) {
      if constexpr (IN_BF16) {
        const unsigned short* ap = (const unsigned short*)Ain + (size_t)arow * 64 + g * 8;
        a0 = *(const bf16x8*)ap;
        a1 = *(const bf16x8*)(ap + 32);
      } else {
        const float* ap = (const float*)Ain + (size_t)arow * 64 + g * 8;
        a0 = pack8(*(const f32x4*)ap, *(const f32x4*)(ap + 4));
        a1 = pack8(*(const f32x4*)(ap + 32), *(const f32x4*)(ap + 36));
      }
    } else {
#pragma unroll
      for (int j = 0; j < 8; ++j) { a0[j] = 0; a1[j] = 0; }
    }
    f32x4 acc[4];
#pragma unroll
    for (int nb = 0; nb < 4; ++nb) {
      acc[nb] = (f32x4){bv[nb], bv[nb], bv[nb], bv[nb]};
      acc[nb] = __builtin_amdgcn_mfma_f32_16x16x32_bf16(a0, bfrag[nb][0], acc[nb], 0, 0, 0);
      acc[nb] = __builtin_amdgcn_mfma_f32_16x16x32_bf16(a1, bfrag[nb][1], acc[nb], 0, 0, 0);
    }
#pragma unroll
    for (int nb = 0; nb < 4; ++nb)
#pragma unroll
      for (int r = 0; r < 4; ++r) {
        int orow = m0 + g * 4 + r;
        if (orow < M) {
          float val = acc[nb][r];
          size_t oidx = (size_t)orow * 64 + nb * 16 + n15;
          if constexpr (OUT_BF16) ((unsigned short*)Out)[oidx] = f2bf(val);
          else                    ((float*)Out)[oidx] = val;
        }
      }
  }
}

// Fused q/k/v: 3 weight sets resident, hx read once, bf16 outputs.
__global__ void __launch_bounds__(256) qkv3_kernel(const float* __restrict__ hx,
    const float* __restrict__ Wq, const float* __restrict__ bq,
    const float* __restrict__ Wk, const float* __restrict__ bk,
    const float* __restrict__ Wv, const float* __restrict__ bv,
    unsigned short* __restrict__ q, unsigned short* __restrict__ k,
    unsigned short* __restrict__ v, int M) {
  const int tid = threadIdx.x;
  const int l = tid & 63;
  const int g = l >> 4;
  const int n15 = l & 15;
  const float* Ws[3] = {Wq, Wk, Wv};
  const float* bs[3] = {bq, bk, bv};
  unsigned short* outs[3] = {q, k, v};

  bf16x8 bfrag[3][4][2];
  float bvv[3][4];
#pragma unroll
  for (int w = 0; w < 3; ++w)
#pragma unroll
    for (int nb = 0; nb < 4; ++nb) {
      bvv[w][nb] = bs[w][nb * 16 + n15];
#pragma unroll
      for (int kb = 0; kb < 2; ++kb)
#pragma unroll
        for (int j = 0; j < 8; ++j)
          bfrag[w][nb][kb][j] = (short)f2bf(Ws[w][(kb * 32 + g * 8 + j) * 64 + nb * 16 + n15]);
    }

  int wid = (blockIdx.x * blockDim.x + tid) >> 6;
  int nw = (gridDim.x * blockDim.x) >> 6;
  int ntiles = (M + 15) >> 4;
  for (int t = wid; t < ntiles; t += nw) {
    int m0 = t << 4;
    int arow = m0 + n15;
    bf16x8 a0, a1;
    if (arow < M) {
      const float* ap = hx + (size_t)arow * 64 + g * 8;
      a0 = pack8(*(const f32x4*)ap, *(const f32x4*)(ap + 4));
      a1 = pack8(*(const f32x4*)(ap + 32), *(const f32x4*)(ap + 36));
    } else {
#pragma unroll
      for (int j = 0; j < 8; ++j) { a0[j] = 0; a1[j] = 0; }
    }
#pragma unroll
    for (int w = 0; w < 3; ++w) {
      f32x4 acc[4];
#pragma unroll
      for (int nb = 0; nb < 4; ++nb) {
        acc[nb] = (f32x4){bvv[w][nb], bvv[w][nb], bvv[w][nb], bvv[w][nb]};
        acc[nb] = __builtin_amdgcn_mfma_f32_16x16x32_bf16(a0, bfrag[w][nb][0], acc[nb], 0, 0, 0);
        acc[nb] = __builtin_amdgcn_mfma_f32_16x16x32_bf16(a1, bfrag[w][nb][1], acc[nb], 0, 0, 0);
      }
#pragma unroll
      for (int nb = 0; nb < 4; ++nb)
#pragma unroll
        for (int r = 0; r < 4; ++r) {
          int orow = m0 + g * 4 + r;
          if (orow < M)
            outs[w][(size_t)orow * 64 + nb * 16 + n15] = f2bf(acc[nb][r]);
        }
    }
  }
}

// ---------------- Fused edge pipeline: TWO independent 16-edge tiles per wave -------
// Separate __shared__ objects for tile A and B (no alias) let the scheduler
// interleave the two dependent chains (qk gather -> p -> LDS rt -> LDS rt -> MFMA),
// doubling ILP per wave. Stores for a clamped duplicate tile are idempotent.
__global__ void __launch_bounds__(256) edge_fused_kernel(
    const float* __restrict__ he,
    const int* __restrict__ rowi, const int* __restrict__ coli,
    const int* __restrict__ eslot,
    const unsigned short* __restrict__ qb, const unsigned short* __restrict__ kbuf,
    const float* __restrict__ We, const float* __restrict__ be,
    const float* __restrict__ Woe, const float* __restrict__ boe,
    float* __restrict__ oe, float* __restrict__ escores, int E) {
  const int tid = threadIdx.x;
  const int wv = tid >> 6;
  const int l = tid & 63;
  const int g = l >> 4;
  const int n15 = l & 15;
  const int h = n15 & 7;

  __shared__ float sA[4][160], sB[4][160];
  __shared__ unsigned short fA[4][16 * 72], fB[4][16 * 72];

  bf16x8 bfE[4][2], bfO[4][2];
  float beV[4], boV[4];
#pragma unroll
  for (int nb = 0; nb < 4; ++nb) {
    beV[nb] = be[nb * 16 + n15];
    boV[nb] = boe[nb * 16 + n15];
#pragma unroll
    for (int kb = 0; kb < 2; ++kb)
#pragma unroll
      for (int j = 0; j < 8; ++j) {
        bfE[nb][kb][j] = (short)f2bf(We[(kb * 32 + g * 8 + j) * 64 + nb * 16 + n15]);
        bfO[nb][kb][j] = (short)f2bf(Woe[(kb * 32 + g * 8 + j) * 64 + nb * 16 + n15]);
      }
  }

  const int ntiles = (E + 15) >> 4;
  const int nit = (ntiles + 3) >> 2;
  const int stride = gridDim.x;

  for (int itA = blockIdx.x; itA < nit; itA += 2 * stride) {
    const int itB = (itA + stride < nit) ? (itA + stride) : itA;  // clamp -> duplicate
    const int m0A = ((itA << 2) + wv) << 4;
    const int m0B = ((itB << 2) + wv) << 4;
    const int esA = min(m0A + n15, E - 1);
    const int esB = min(m0B + n15, E - 1);

    // indices + he rows for both tiles (issue all loads up front)
    const int rqA = rowi[esA], rcA = coli[esA], slA = eslot[esA];
    const int rqB = rowi[esB], rcB = coli[esB], slB = eslot[esB];
    const float* apA = he + (size_t)esA * 64 + g * 8;
    const float* apB = he + (size_t)esB * 64 + g * 8;
    f32x4 hA0 = *(const f32x4*)apA,        hA1 = *(const f32x4*)(apA + 4);
    f32x4 hA2 = *(const f32x4*)(apA + 32), hA3 = *(const f32x4*)(apA + 36);
    f32x4 hB0 = *(const f32x4*)apB,        hB1 = *(const f32x4*)(apB + 4);
    f32x4 hB2 = *(const f32x4*)(apB + 32), hB3 = *(const f32x4*)(apB + 36);

    // elin for both tiles (kills he registers)
    bf16x8 aA0 = pack8(hA0, hA1), aA1 = pack8(hA2, hA3);
    bf16x8 aB0 = pack8(hB0, hB1), aB1 = pack8(hB2, hB3);
    f32x4 accA[4], accB[4];
#pragma unroll
    for (int nb = 0; nb < 4; ++nb) {
      accA[nb] = (f32x4){beV[nb], beV[nb], beV[nb], beV[nb]};
      accA[nb] = __builtin_amdgcn_mfma_f32_16x16x32_bf16(aA0, bfE[nb][0], accA[nb], 0, 0, 0);
      accA[nb] = __builtin_amdgcn_mfma_f32_16x16x32_bf16(aA1, bfE[nb][1], accA[nb], 0, 0, 0);
      accB[nb] = (f32x4){beV[nb], beV[nb], beV[nb], beV[nb]};
      accB[nb] = __builtin_amdgcn_mfma_f32_16x16x32_bf16(aB0, bfE[nb][0], accB[nb], 0, 0, 0);
      accB[nb] = __builtin_amdgcn_mfma_f32_16x16x32_bf16(aB1, bfE[nb][1], accB[nb], 0, 0, 0);
    }

    // qk gathers for both tiles
    const unsigned short* qpA = qb   + (size_t)rqA * 64 + g * 16;
    const unsigned short* kpA = kbuf + (size_t)rcA * 64 + g * 16;
    const unsigned short* qpB = qb   + (size_t)rqB * 64 + g * 16;
    const unsigned short* kpB = kbuf + (size_t)rcB * 64 + g * 16;
    bf16x8 qA0 = *(const bf16x8*)qpA, qA1 = *(const bf16x8*)(qpA + 8);
    bf16x8 kA0 = *(const bf16x8*)kpA, kA1 = *(const bf16x8*)(kpA + 8);
    bf16x8 qB0 = *(const bf16x8*)qpB, qB1 = *(const bf16x8*)(qpB + 8);
    bf16x8 kB0 = *(const bf16x8*)kpB, kB1 = *(const bf16x8*)(kpB + 8);

    // per-head gates (sum nb quadrants + pair n15<->n15+8; fold 1/sqrt(8))
    float gcA[4], gcB[4];
#pragma unroll
    for (int r = 0; r < 4; ++r) {
      float sa = accA[0][r] + accA[1][r] + accA[2][r] + accA[3][r];
      sa += __shfl_xor(sa, 8, 64);
      gcA[r] = sa * 0.35355339059327373f;
      float sb = accB[0][r] + accB[1][r] + accB[2][r] + accB[3][r];
      sb += __shfl_xor(sb, 8, 64);
      gcB[r] = sb * 0.35355339059327373f;
    }

    // q.k per head (p[j] = head j of edge n15 after g-reduction)
    float pA[8], pB[8];
#pragma unroll
    for (int j = 0; j < 8; ++j) {
      pA[j] = bf2f((unsigned short)qA0[j]) * bf2f((unsigned short)kA0[j])
            + bf2f((unsigned short)qA1[j]) * bf2f((unsigned short)kA1[j]);
      pB[j] = bf2f((unsigned short)qB0[j]) * bf2f((unsigned short)kB0[j])
            + bf2f((unsigned short)qB1[j]) * bf2f((unsigned short)kB1[j]);
    }
#pragma unroll
    for (int j = 0; j < 8; ++j) {
      pA[j] += __shfl_xor(pA[j], 16, 64);
      pA[j] += __shfl_xor(pA[j], 32, 64);
      pB[j] += __shfl_xor(pB[j], 16, 64);
      pB[j] += __shfl_xor(pB[j], 32, 64);
    }

    // p -> LDS (edge-row layout), both tiles, then re-read in C-row layout
    if (l < 16) {
      float2* spA = (float2*)&sA[wv][n15 * 10];
      float2* spB = (float2*)&sB[wv][n15 * 10];
#pragma unroll
      for (int j = 0; j < 4; ++j) {
        spA[j] = make_float2(pA[2 * j], pA[2 * j + 1]);
        spB[j] = make_float2(pB[2 * j], pB[2 * j + 1]);
      }
    }
    float srA[4], srB[4];
#pragma unroll
    for (int r = 0; r < 4; ++r) {
      srA[r] = sA[wv][(g * 4 + r) * 10 + h] * gcA[r];
      srB[r] = sB[wv][(g * 4 + r) * 10 + h] * gcB[r];
    }

    // gated scores out in CSR slot order
#pragma unroll
    for (int r = 0; r < 4; ++r) {
      int slotA = __shfl(slA, g * 4 + r, 64);
      int slotB = __shfl(slB, g * 4 + r, 64);
      if (n15 < 8 && m0A + g * 4 + r < E) escores[(size_t)slotA * 8 + n15] = srA[r];
      if (n15 < 8 && m0B + g * 4 + r < E) escores[(size_t)slotB * 8 + n15] = srB[r];
    }

    // feat = s*elin -> LDS transpose tiles
#pragma unroll
    for (int nb = 0; nb < 4; ++nb)
#pragma unroll
      for (int r = 0; r < 4; ++r) {
        fA[wv][(g * 4 + r) * 72 + nb * 16 + n15] = f2bf(srA[r] * accA[nb][r]);
        fB[wv][(g * 4 + r) * 72 + nb * 16 + n15] = f2bf(srB[r] * accB[nb][r]);
      }
    const unsigned short* fpA = &fA[wv][n15 * 72 + g * 8];
    const unsigned short* fpB = &fB[wv][n15 * 72 + g * 8];
    bf16x8 oA0 = *(const bf16x8*)fpA, oA1 = *(const bf16x8*)(fpA + 32);
    bf16x8 oB0 = *(const bf16x8*)fpB, oB1 = *(const bf16x8*)(fpB + 32);
#pragma unroll
    for (int nb = 0; nb < 4; ++nb) {
      f32x4 cA = (f32x4){boV[nb], boV[nb], boV[nb], boV[nb]};
      cA = __builtin_amdgcn_mfma_f32_16x16x32_bf16(oA0, bfO[nb][0], cA, 0, 0, 0);
      cA = __builtin_amdgcn_mfma_f32_16x16x32_bf16(oA1, bfO[nb][1], cA, 0, 0, 0);
      f32x4 cB = (f32x4){boV[nb], boV[nb], boV[nb], boV[nb]};
      cB = __builtin_amdgcn_mfma_f32_16x16x32_bf16(oB0, bfO[nb][0], cB, 0, 0, 0);
      cB = __builtin_amdgcn_mfma_f32_16x16x32_bf16(oB1, bfO[nb][1], cB, 0, 0, 0);
#pragma unroll
      for (int r = 0; r < 4; ++r) {
        int orA = m0A + g * 4 + r;
        int orB = m0B + g * 4 + r;
        if (orA < E) oe[(size_t)orA * 64 + nb * 16 + n15] = cA[r];
        if (orB < E) oe[(size_t)orB * 64 + nb * 16 + n15] = cB[r];
      }
    }
  }
}

// ---------------- CSR build ----------------
__global__ void zero_kernel(int* __restrict__ p, int n) {
  int i = blockIdx.x * blockDim.x + threadIdx.x;
  if (i < n) p[i] = 0;
}

__global__ void hist_kernel(const int* __restrict__ row, int* __restrict__ deg, int E) {
  int gid = blockIdx.x * blockDim.x + threadIdx.x;
  if (gid < E) atomicAdd(&deg[row[gid]], 1);
}

#define SCAN_B 256
#define SCAN_E 8
__global__ void scan1_kernel(const int* __restrict__ deg, int* __restrict__ rowptr,
                             int* __restrict__ blksum, int n) {
  __shared__ int sh[SCAN_B];
  int base = blockIdx.x * (SCAN_B * SCAN_E) + threadIdx.x * SCAN_E;
  int v[SCAN_E];
  int s = 0;
#pragma unroll
  for (int j = 0; j < SCAN_E; ++j) {
    v[j] = (base + j < n) ? deg[base + j] : 0;
    s += v[j];
  }
  sh[threadIdx.x] = s;
  __syncthreads();
  for (int off = 1; off < SCAN_B; off <<= 1) {
    int t = (threadIdx.x >= off) ? sh[threadIdx.x - off] : 0;
    __syncthreads();
    sh[threadIdx.x] += t;
    __syncthreads();
  }
  if (threadIdx.x == SCAN_B - 1) blksum[blockIdx.x] = sh[SCAN_B - 1];
  int run = sh[threadIdx.x] - s;
#pragma unroll
  for (int j = 0; j < SCAN_E; ++j) {
    if (base + j < n) rowptr[base + j] = run;
    run += v[j];
  }
}

__global__ void scan2_kernel(int* __restrict__ blksum, int nb) {
  __shared__ int sh[SCAN_B];
  int v = (threadIdx.x < nb) ? blksum[threadIdx.x] : 0;
  sh[threadIdx.x] = v;
  __syncthreads();
  for (int off = 1; off < SCAN_B; off <<= 1) {
    int t = (threadIdx.x >= off) ? sh[threadIdx.x - off] : 0;
    __syncthreads();
    sh[threadIdx.x] += t;
    __syncthreads();
  }
  if (threadIdx.x < nb) blksum[threadIdx.x] = sh[threadIdx.x] - v;
}

__global__ void scan3_kernel(int* __restrict__ rowptr, int* __restrict__ cursor,
                             const int* __restrict__ blksum, int n) {
  int i = blockIdx.x * blockDim.x + threadIdx.x;
  if (i >= n) return;
  int v = rowptr[i] + blksum[i / (SCAN_B * SCAN_E)];
  rowptr[i] = v;
  cursor[i] = v;
}

// records eslot[e] so scores can be written in CSR order by edge_fused
__global__ void scatter_kernel(const int* __restrict__ row, const int* __restrict__ col,
                               int* __restrict__ cursor, int* __restrict__ eslot,
                               int* __restrict__ ecol, int E) {
  int gid = blockIdx.x * blockDim.x + threadIdx.x;
  if (gid >= E) return;
  int r = row[gid];
  int slot = atomicAdd(&cursor[r], 1);
  eslot[gid] = slot;
  ecol[slot] = col[gid];
}

// One wave per row, 4 edges in flight per iteration.
// lane = (gi, j): group gi handles edges i = gi, gi+4, ...; lane covers cols j*4..j*4+3.
// v: one ushort4 (8B) per lane; escores: one float4 per lane (heads 4*(j&1)..+3,
// matching cols (4j+m)&7). Cross-group shfl_xor(16,32) reduce; f32x4 store.
__global__ void __launch_bounds__(256) row_attn_kernel(const float* __restrict__ escores,
    const int* __restrict__ rowptr, const int* __restrict__ deg,
    const int* __restrict__ ecol,
    const unsigned short* __restrict__ vb, float* __restrict__ hout, int n) {
  int gid = blockIdx.x * blockDim.x + threadIdx.x;
  int r = gid >> 6, lane = threadIdx.x & 63;
  if (r >= n) return;
  int gi = lane >> 4, j = lane & 15;
  int start = rowptr[r], dg = deg[r];

  f32x4 acc = (f32x4){0.f, 0.f, 0.f, 0.f};
  f32x4 den = (f32x4){0.f, 0.f, 0.f, 0.f};
  for (int i = gi; i < dg; i += 4) {
    int idx = start + i;
    int c = ecol[idx];
    f32x4 sv = *(const f32x4*)(escores + (size_t)idx * 8 + 4 * (j & 1));
    u16x4 vv = *(const u16x4*)(vb + (size_t)c * 64 + j * 4);
#pragma unroll
    for (int m = 0; m < 4; ++m) {
      float ex = __expf(sv[m]);
      den[m] += ex;
      acc[m] += ex * bf2f(vv[m]);
    }
  }
  // reduce across the 4 groups
#pragma unroll
  for (int m = 0; m < 4; ++m) {
    acc[m] += __shfl_xor(acc[m], 16, 64);
    acc[m] += __shfl_xor(acc[m], 32, 64);
    den[m] += __shfl_xor(den[m], 16, 64);
    den[m] += __shfl_xor(den[m], 32, 64);
  }
  if (gi == 0) {
    f32x4 o;
#pragma unroll
    for (int m = 0; m < 4; ++m) o[m] = (dg > 0) ? acc[m] / den[m] : 0.f;
    *(f32x4*)(hout + (size_t)r * 64 + j * 4) = o;
  }
}

extern "C" void kernel_launch(void* const* d_in, const int* in_sizes, int n_in,
                              void* d_out, int out_size, void* d_ws, size_t ws_size,
                              hipStream_t stream) {
  const float* hx  = (const float*)d_in[0];
  const float* he  = (const float*)d_in[1];
  const int*   row = (const int*)d_in[2];
  const int*   col = (const int*)d_in[3];
  const float* Wq = (const float*)d_in[4],  *bq = (const float*)d_in[5];
  const float* Wk = (const float*)d_in[6],  *bk = (const float*)d_in[7];
  const float* Wv = (const float*)d_in[8],  *bv = (const float*)d_in[9];
  const float* We = (const float*)d_in[10], *be = (const float*)d_in[11];
  const float* Woh = (const float*)d_in[12], *boh = (const float*)d_in[13];
  const float* Woe = (const float*)d_in[14], *boe = (const float*)d_in[15];

  const int n = in_sizes[0] / 64;
  const int E = in_sizes[2];

  float* out = (float*)d_out;
  float* oh = out;                   // n*64 fp32
  float* oe = out + (size_t)n * 64;  // E*64 fp32

  // ws: qb,kb,vbuf (n*64 bf16) | escores (E*8 f32, CSR order) | hout (n*64 f32)
  //   | deg,rowptr,cursor (n int) | blksum (256) | eslot (E) | ecol (E)
  unsigned short* qb   = (unsigned short*)d_ws;
  unsigned short* kb   = qb + (size_t)n * 64;
  unsigned short* vbuf = kb + (size_t)n * 64;
  float* escores = (float*)(vbuf + (size_t)n * 64);
  float* hout    = escores + (size_t)E * 8;

  int* deg    = (int*)(hout + (size_t)n * 64);
  int* rowptr = deg + n;
  int* cursor = rowptr + n;
  int* blksum = cursor + n;
  int* eslot  = blksum + 256;
  int* ecol   = eslot + (size_t)E;

  const int nb_scan = (n + SCAN_B * SCAN_E - 1) / (SCAN_B * SCAN_E);

  // CSR build first (depends only on row/col) so edge_fused can scatter scores.
  zero_kernel<<<(n + 255) / 256, 256, 0, stream>>>(deg, n);
  hist_kernel<<<(E + 255) / 256, 256, 0, stream>>>(row, deg, E);
  scan1_kernel<<<nb_scan, SCAN_B, 0, stream>>>(deg, rowptr, blksum, n);
  scan2_kernel<<<1, SCAN_B, 0, stream>>>(blksum, nb_scan);
  scan3_kernel<<<(n + 255) / 256, 256, 0, stream>>>(rowptr, cursor, blksum, n);
  scatter_kernel<<<(E + 255) / 256, 256, 0, stream>>>(row, col, cursor, eslot, ecol, E);

  qkv3_kernel<<<512, 256, 0, stream>>>(hx, Wq, bq, Wk, bk, Wv, bv, qb, kb, vbuf, n);
  edge_fused_kernel<<<2048, 256, 0, stream>>>(he, row, col, eslot, qb, kb, We, be,
                                              Woe, boe, oe, escores, E);

  row_attn_kernel<<<(n + 3) / 4, 256, 0, stream>>>(escores, rowptr, deg, ecol,
                                                   vbuf, hout, n);
  gemm64_kernel<false, false><<<512, 256, 0, stream>>>(hout, Woh, boh, oh, n);
}